// Round 1
// baseline (251.414 us; speedup 1.0000x reference)
//
#include <hip/hip_runtime.h>

typedef __bf16 bf16;
typedef __bf16 bf16x8 __attribute__((ext_vector_type(8)));
typedef float f32x4 __attribute__((ext_vector_type(4)));

#define MFMA16(a, b, c) __builtin_amdgcn_mfma_f32_16x16x32_bf16((a), (b), (c), 0, 0, 0)

// ---------------------------------------------------------------------------
// K1: transpose x [256][4096] f32 -> xbf_t [4096][256] bf16 (contiguous K=c)
// ---------------------------------------------------------------------------
__global__ void k_transpose_x(const float* __restrict__ x, bf16* __restrict__ xt) {
    int n = blockIdx.x;          // 4096
    int c = threadIdx.x;         // 256
    xt[n * 256 + c] = (bf16)x[c * 4096 + n];
}

// ---------------------------------------------------------------------------
// K2: fused weights Wq/Wk/Wv = w2 @ w1  [512][256] bf16, plus wo/wg -> bf16
// ---------------------------------------------------------------------------
__global__ void k_prep_w(const float* __restrict__ wq1, const float* __restrict__ wk1,
                         const float* __restrict__ wv1, const float* __restrict__ wq2,
                         const float* __restrict__ wk2, const float* __restrict__ wv2,
                         const float* __restrict__ wo, const float* __restrict__ wg,
                         bf16* __restrict__ Wq, bf16* __restrict__ Wk, bf16* __restrict__ Wv,
                         bf16* __restrict__ wo_bf, bf16* __restrict__ wg_bf) {
    int t = blockIdx.x * 256 + threadIdx.x;
    if (t < 393216) {                       // 3 * 512 * 256
        int which = t >> 17;                // 131072 each
        int rem = t & 131071;
        int o = rem >> 8, c = rem & 255;
        const float* w1 = which == 0 ? wq1 : which == 1 ? wk1 : wv1;
        const float* w2 = which == 0 ? wq2 : which == 1 ? wk2 : wv2;
        float acc = 0.f;
#pragma unroll
        for (int j = 0; j < 32; ++j) acc += w2[o * 32 + j] * w1[j * 256 + c];
        bf16* W = which == 0 ? Wq : which == 1 ? Wk : Wv;
        W[o * 256 + c] = (bf16)acc;
    } else if (t < 524288) {                // wo: 256*512
        int idx = t - 393216;
        wo_bf[idx] = (bf16)wo[idx];
    } else if (t < 589824) {                // wg: 256*256
        int idx = t - 524288;
        wg_bf[idx] = (bf16)wg[idx];
    }
}

// ---------------------------------------------------------------------------
// Generic GEMM-NT: C[i][j] = sum_k A[i][k] * B[j][k].  A:[M][K] B:[N][K] bf16.
// Block = 4 waves, tile 128(i) x 64(j). grid = (N/64, M/128).
// MODE 0: QK-proj   -> bf16 q_buf[h][n][d], i=n j=o, scale applied
// MODE 1: V-proj    -> bf16 vT[o][n],       i=o j=n
// MODE 2: out-proj  -> f32  y[c][n] = acc + bias[c]
// MODE 3: gate      -> f32  d_out[c][n] = mul[c][n] * sigmoid(acc + bias[c])
// ---------------------------------------------------------------------------
template <int MODE>
__launch_bounds__(256)
__global__ void k_gemm_nt(const bf16* __restrict__ A, const bf16* __restrict__ B,
                          int K, float scale, void* __restrict__ outp,
                          const float* __restrict__ bias, const float* __restrict__ mul) {
    const int lane = threadIdx.x & 63;
    const int w = threadIdx.x >> 6;
    const int i0 = blockIdx.y * 128 + w * 32;
    const int j0 = blockIdx.x * 64;
    const int lrow = lane & 15;
    const int lk = (lane >> 4) * 8;

    f32x4 acc[2][4];
#pragma unroll
    for (int a = 0; a < 2; ++a)
#pragma unroll
        for (int b = 0; b < 4; ++b) acc[a][b] = (f32x4){0.f, 0.f, 0.f, 0.f};

    for (int k0 = 0; k0 < K; k0 += 32) {
        bf16x8 af[2], bfr[4];
#pragma unroll
        for (int qs = 0; qs < 2; ++qs)
            af[qs] = *(const bf16x8*)(A + (size_t)(i0 + qs * 16 + lrow) * K + k0 + lk);
#pragma unroll
        for (int js = 0; js < 4; ++js)
            bfr[js] = *(const bf16x8*)(B + (size_t)(j0 + js * 16 + lrow) * K + k0 + lk);
#pragma unroll
        for (int qs = 0; qs < 2; ++qs)
#pragma unroll
            for (int js = 0; js < 4; ++js)
                acc[qs][js] = MFMA16(af[qs], bfr[js], acc[qs][js]);
    }

    const int rbase = (lane >> 4) * 4;
#pragma unroll
    for (int qs = 0; qs < 2; ++qs)
#pragma unroll
        for (int js = 0; js < 4; ++js)
#pragma unroll
            for (int r = 0; r < 4; ++r) {
                int i = i0 + qs * 16 + rbase + r;
                int j = j0 + js * 16 + lrow;
                float v = acc[qs][js][r];
                if (MODE == 0) {
                    ((bf16*)outp)[(size_t)(j >> 6) * (4096 * 64) + (size_t)i * 64 + (j & 63)] =
                        (bf16)(v * scale);
                } else if (MODE == 1) {
                    ((bf16*)outp)[(size_t)i * 4096 + j] = (bf16)v;
                } else if (MODE == 2) {
                    ((float*)outp)[(size_t)i * 4096 + j] = v + bias[i];
                } else {
                    float g = v + bias[i];
                    float sg = 1.f / (1.f + __expf(-g));
                    ((float*)outp)[(size_t)i * 4096 + j] = mul[(size_t)i * 4096 + j] * sg;
                }
            }
}

// ---------------------------------------------------------------------------
// K4: flash attention.  q,k: [8][4096][64] bf16 (q pre-scaled by 1/8),
// vT: [8][64][4096] bf16.  out o_buf: [4096][512] bf16.
// grid = 8 heads * 32 q-tiles(128 rows); block = 4 waves * 32 q-rows each.
// ---------------------------------------------------------------------------
__launch_bounds__(256)
__global__ void k_attn(const bf16* __restrict__ q, const bf16* __restrict__ k,
                       const bf16* __restrict__ vT, bf16* __restrict__ o) {
    __shared__ bf16 plds[4][32 * 64];
    const int lane = threadIdx.x & 63;
    const int w = threadIdx.x >> 6;
    const int h = blockIdx.x >> 5;
    const int qt = blockIdx.x & 31;
    const int qbase = qt * 128 + w * 32;
    const int lrow = lane & 15;
    const int lk = (lane >> 4) * 8;
    const int rbase = (lane >> 4) * 4;

    const bf16* qh = q + (size_t)h * 4096 * 64;
    const bf16* kh = k + (size_t)h * 4096 * 64;
    const bf16* vh = vT + (size_t)h * 64 * 4096;
    bf16* mylds = plds[w];

    bf16x8 aq[2][2];
#pragma unroll
    for (int qs = 0; qs < 2; ++qs)
#pragma unroll
        for (int ks = 0; ks < 2; ++ks)
            aq[qs][ks] = *(const bf16x8*)(qh + (size_t)(qbase + qs * 16 + lrow) * 64 + ks * 32 + lk);

    f32x4 accO[2][4];
    float m_run[2][4], l_run[2][4];
#pragma unroll
    for (int qs = 0; qs < 2; ++qs) {
#pragma unroll
        for (int ds = 0; ds < 4; ++ds) accO[qs][ds] = (f32x4){0.f, 0.f, 0.f, 0.f};
#pragma unroll
        for (int r = 0; r < 4; ++r) { m_run[qs][r] = -1e30f; l_run[qs][r] = 0.f; }
    }

    for (int t = 0; t < 64; ++t) {
        const int kb = t * 64;
        // ---- S = Q K^T (Q pre-scaled) ----
        bf16x8 bk[2][4];
#pragma unroll
        for (int ks = 0; ks < 2; ++ks)
#pragma unroll
            for (int js = 0; js < 4; ++js)
                bk[ks][js] = *(const bf16x8*)(kh + (size_t)(kb + js * 16 + lrow) * 64 + ks * 32 + lk);
        f32x4 s[2][4];
#pragma unroll
        for (int qs = 0; qs < 2; ++qs)
#pragma unroll
            for (int js = 0; js < 4; ++js) s[qs][js] = (f32x4){0.f, 0.f, 0.f, 0.f};
#pragma unroll
        for (int ks = 0; ks < 2; ++ks)
#pragma unroll
            for (int qs = 0; qs < 2; ++qs)
#pragma unroll
                for (int js = 0; js < 4; ++js)
                    s[qs][js] = MFMA16(aq[qs][ks], bk[ks][js], s[qs][js]);

        // ---- online softmax ----
#pragma unroll
        for (int qs = 0; qs < 2; ++qs) {
            float mnew[4], sc[4];
#pragma unroll
            for (int r = 0; r < 4; ++r) {
                float rm = fmaxf(fmaxf(s[qs][0][r], s[qs][1][r]), fmaxf(s[qs][2][r], s[qs][3][r]));
                rm = fmaxf(rm, __shfl_xor(rm, 1, 16));
                rm = fmaxf(rm, __shfl_xor(rm, 2, 16));
                rm = fmaxf(rm, __shfl_xor(rm, 4, 16));
                rm = fmaxf(rm, __shfl_xor(rm, 8, 16));
                mnew[r] = fmaxf(m_run[qs][r], rm);
                sc[r] = __expf(m_run[qs][r] - mnew[r]);
                m_run[qs][r] = mnew[r];
                l_run[qs][r] *= sc[r];
            }
#pragma unroll
            for (int js = 0; js < 4; ++js)
#pragma unroll
                for (int r = 0; r < 4; ++r) {
                    float p = __expf(s[qs][js][r] - mnew[r]);
                    l_run[qs][r] += p;
                    int row = qs * 16 + rbase + r;
                    int idx = (row * 64 + js * 16 + lrow) ^ ((row & 7) << 3);
                    mylds[idx] = (bf16)p;
                }
#pragma unroll
            for (int ds = 0; ds < 4; ++ds)
#pragma unroll
                for (int r = 0; r < 4; ++r) accO[qs][ds][r] *= sc[r];
        }

        // ---- O += P V ----
#pragma unroll
        for (int ks2 = 0; ks2 < 2; ++ks2) {
            bf16x8 ap[2], bv[4];
#pragma unroll
            for (int qs = 0; qs < 2; ++qs) {
                int row = qs * 16 + lrow;
                int idx = (row * 64 + ks2 * 32 + lk) ^ ((row & 7) << 3);
                ap[qs] = *(const bf16x8*)(mylds + idx);
            }
#pragma unroll
            for (int ds = 0; ds < 4; ++ds)
                bv[ds] = *(const bf16x8*)(vh + (size_t)(ds * 16 + lrow) * 4096 + kb + ks2 * 32 + lk);
#pragma unroll
            for (int qs = 0; qs < 2; ++qs)
#pragma unroll
                for (int ds = 0; ds < 4; ++ds)
                    accO[qs][ds] = MFMA16(ap[qs], bv[ds], accO[qs][ds]);
        }
    }

    // ---- finalize: divide by row-sum, write [n][512] ----
#pragma unroll
    for (int qs = 0; qs < 2; ++qs) {
        float inv[4];
#pragma unroll
        for (int r = 0; r < 4; ++r) {
            float lv = l_run[qs][r];
            lv += __shfl_xor(lv, 1, 16);
            lv += __shfl_xor(lv, 2, 16);
            lv += __shfl_xor(lv, 4, 16);
            lv += __shfl_xor(lv, 8, 16);
            inv[r] = 1.f / lv;
        }
#pragma unroll
        for (int ds = 0; ds < 4; ++ds)
#pragma unroll
            for (int r = 0; r < 4; ++r) {
                float val = accO[qs][ds][r] * inv[r];
                int row = qbase + qs * 16 + rbase + r;
                o[(size_t)row * 512 + h * 64 + ds * 16 + lrow] = (bf16)val;
            }
    }
}

// ---------------------------------------------------------------------------
// K6: depthwise 3x3 conv (SAME).  y:[256][64][64] f32 -> dwout f32 [c][n]
// and dw_tbf bf16 [n][c] for the gate GEMM.
// ---------------------------------------------------------------------------
__global__ void k_dw(const float* __restrict__ y, const float* __restrict__ wdw,
                     const float* __restrict__ bdw, float* __restrict__ dwout,
                     bf16* __restrict__ dwt) {
    int t = blockIdx.x * 256 + threadIdx.x;   // 1M
    int c = t >> 12, n = t & 4095, yy = n >> 6, xx = n & 63;
    float acc = bdw[c];
    const float* yc = y + (size_t)c * 4096;
#pragma unroll
    for (int ky = 0; ky < 3; ++ky) {
        int ry = yy + ky - 1;
        if ((unsigned)ry < 64u) {
#pragma unroll
            for (int kx = 0; kx < 3; ++kx) {
                int rx = xx + kx - 1;
                if ((unsigned)rx < 64u) acc += wdw[c * 9 + ky * 3 + kx] * yc[ry * 64 + rx];
            }
        }
    }
    dwout[t] = acc;               // t == c*4096 + n
    dwt[n * 256 + c] = (bf16)acc;
}

// ---------------------------------------------------------------------------
extern "C" void kernel_launch(void* const* d_in, const int* in_sizes, int n_in,
                              void* d_out, int out_size, void* d_ws, size_t ws_size,
                              hipStream_t stream) {
    const float* x   = (const float*)d_in[0];
    const float* wq1 = (const float*)d_in[1];
    const float* wk1 = (const float*)d_in[2];
    const float* wv1 = (const float*)d_in[3];
    const float* wq2 = (const float*)d_in[4];
    const float* wk2 = (const float*)d_in[5];
    const float* wv2 = (const float*)d_in[6];
    const float* wo  = (const float*)d_in[7];
    const float* bo  = (const float*)d_in[8];
    const float* wdw = (const float*)d_in[9];
    const float* bdw = (const float*)d_in[10];
    const float* wg  = (const float*)d_in[11];
    const float* bg  = (const float*)d_in[12];

    char* ws = (char*)d_ws;
    size_t off = 0;
    auto alloc = [&](size_t bytes) {
        char* p = ws + off;
        off += (bytes + 255) & ~(size_t)255;
        return p;
    };
    bf16*  xbf   = (bf16*)alloc((size_t)4096 * 256 * 2);   // x^T bf16
    bf16*  Wq    = (bf16*)alloc((size_t)512 * 256 * 2);
    bf16*  Wk    = (bf16*)alloc((size_t)512 * 256 * 2);
    bf16*  Wv    = (bf16*)alloc((size_t)512 * 256 * 2);
    bf16*  wo_bf = (bf16*)alloc((size_t)256 * 512 * 2);
    bf16*  wg_bf = (bf16*)alloc((size_t)256 * 256 * 2);
    bf16*  q_buf = (bf16*)alloc((size_t)8 * 4096 * 64 * 2);
    bf16*  k_buf = (bf16*)alloc((size_t)8 * 4096 * 64 * 2);
    bf16*  vT    = (bf16*)alloc((size_t)8 * 64 * 4096 * 2);
    bf16*  o_buf = (bf16*)alloc((size_t)4096 * 512 * 2);
    float* ybuf  = (float*)alloc((size_t)256 * 4096 * 4);
    float* dwout = (float*)alloc((size_t)256 * 4096 * 4);
    bf16*  dwt   = (bf16*)alloc((size_t)4096 * 256 * 2);
    (void)ws_size; (void)in_sizes; (void)n_in; (void)out_size;

    k_transpose_x<<<4096, 256, 0, stream>>>(x, xbf);
    k_prep_w<<<2304, 256, 0, stream>>>(wq1, wk1, wv1, wq2, wk2, wv2, wo, wg,
                                       Wq, Wk, Wv, wo_bf, wg_bf);
    // Q,K: C[n][o]  (A = x^T, B = fused W);  Q pre-scaled by 1/sqrt(64)
    k_gemm_nt<0><<<dim3(8, 32), 256, 0, stream>>>(xbf, Wq, 256, 0.125f, q_buf, nullptr, nullptr);
    k_gemm_nt<0><<<dim3(8, 32), 256, 0, stream>>>(xbf, Wk, 256, 1.0f, k_buf, nullptr, nullptr);
    // V: C[o][n]
    k_gemm_nt<1><<<dim3(64, 4), 256, 0, stream>>>(Wv, xbf, 256, 1.0f, vT, nullptr, nullptr);
    // attention
    k_attn<<<256, 256, 0, stream>>>(q_buf, k_buf, vT, o_buf);
    // out-proj: y[c][n] = wo @ O^T + bo
    k_gemm_nt<2><<<dim3(64, 2), 256, 0, stream>>>(wo_bf, o_buf, 512, 1.0f, ybuf, bo, nullptr);
    // depthwise conv
    k_dw<<<4096, 256, 0, stream>>>(ybuf, wdw, bdw, dwout, dwt);
    // gate 1x1 conv + sigmoid + multiply -> d_out
    k_gemm_nt<3><<<dim3(64, 2), 256, 0, stream>>>(wg_bf, dwt, 256, 1.0f, d_out, bg, dwout);
}

// Round 3
// 197.517 us; speedup vs baseline: 1.2729x; 1.2729x over previous
//
#include <hip/hip_runtime.h>

typedef __bf16 bf16;
typedef __bf16 bf16x4 __attribute__((ext_vector_type(4)));
typedef __bf16 bf16x8 __attribute__((ext_vector_type(8)));
typedef float f32x4 __attribute__((ext_vector_type(4)));

#define MFMA16(a, b, c) __builtin_amdgcn_mfma_f32_16x16x32_bf16((a), (b), (c), 0, 0, 0)

__device__ inline float fexp2(float x) {
    float r;
    asm("v_exp_f32 %0, %1" : "=v"(r) : "v"(x));
    return r;
}

// ---------------------------------------------------------------------------
// K1: transpose x [256][4096] f32 -> xt [4096][256] bf16, LDS-tiled 64x64.
// ---------------------------------------------------------------------------
__global__ void k_transpose_x(const float* __restrict__ x, bf16* __restrict__ xt) {
    __shared__ float tile[64][68];          // [c][n], pad 68 (16B-aligned pitch)
    const int t = threadIdx.x;
    const int c0 = (blockIdx.x & 3) * 64;
    const int n0 = (blockIdx.x >> 2) * 64;
    {
        const int cr = t >> 4, nc = (t & 15) * 4;
#pragma unroll
        for (int i = 0; i < 4; ++i) {
            const float4 v = *(const float4*)(x + (size_t)(c0 + cr + i * 16) * 4096 + n0 + nc);
            tile[cr + i * 16][nc + 0] = v.x;
            tile[cr + i * 16][nc + 1] = v.y;
            tile[cr + i * 16][nc + 2] = v.z;
            tile[cr + i * 16][nc + 3] = v.w;
        }
    }
    __syncthreads();
    const int n = t >> 2, cc = (t & 3) * 16;
    bf16x8 o0, o1;
#pragma unroll
    for (int j = 0; j < 8; ++j) o0[j] = (bf16)tile[cc + j][n];
#pragma unroll
    for (int j = 0; j < 8; ++j) o1[j] = (bf16)tile[cc + 8 + j][n];
    bf16* dst = xt + (size_t)(n0 + n) * 256 + c0 + cc;
    *(bf16x8*)dst = o0;
    *(bf16x8*)(dst + 8) = o1;
}

// ---------------------------------------------------------------------------
// K2: fused weights Wq/Wk/Wv = w2 @ w1  [512][256] bf16, plus wo/wg -> bf16
// ---------------------------------------------------------------------------
__global__ void k_prep_w(const float* __restrict__ wq1, const float* __restrict__ wk1,
                         const float* __restrict__ wv1, const float* __restrict__ wq2,
                         const float* __restrict__ wk2, const float* __restrict__ wv2,
                         const float* __restrict__ wo, const float* __restrict__ wg,
                         bf16* __restrict__ Wq, bf16* __restrict__ Wk, bf16* __restrict__ Wv,
                         bf16* __restrict__ wo_bf, bf16* __restrict__ wg_bf) {
    int t = blockIdx.x * 256 + threadIdx.x;
    if (t < 393216) {                       // 3 * 512 * 256
        int which = t >> 17;
        int rem = t & 131071;
        int o = rem >> 8, c = rem & 255;
        const float* w1 = which == 0 ? wq1 : which == 1 ? wk1 : wv1;
        const float* w2 = which == 0 ? wq2 : which == 1 ? wk2 : wv2;
        float acc = 0.f;
#pragma unroll
        for (int j = 0; j < 32; ++j) acc += w2[o * 32 + j] * w1[j * 256 + c];
        bf16* W = which == 0 ? Wq : which == 1 ? Wk : Wv;
        W[o * 256 + c] = (bf16)acc;
    } else if (t < 524288) {                // wo: 256*512
        int idx = t - 393216;
        wo_bf[idx] = (bf16)wo[idx];
    } else if (t < 589824) {                // wg: 256*256
        int idx = t - 524288;
        wg_bf[idx] = (bf16)wg[idx];
    }
}

// ---------------------------------------------------------------------------
// Generic GEMM-NT: C[i][j] = sum_k A[i][k] * B[j][k].  A:[M][K] B:[N][K] bf16.
// Block = 4 waves, tile 128(i) x 64(j). grid = (N/64, M/128).
// MODE 0: QK-proj -> bf16 q_buf[h][n][d] (scale applied)
// MODE 1: V-proj  -> bf16 vT[o][n]
// MODE 2: out-proj-> f32  y[c][n] = acc + bias[c]
// MODE 3: gate    -> f32  d_out[c][n] = mul[c][n] * sigmoid(acc + bias[c])
// ---------------------------------------------------------------------------
template <int MODE>
__launch_bounds__(256)
__global__ void k_gemm_nt(const bf16* __restrict__ A, const bf16* __restrict__ B,
                          int K, float scale, void* __restrict__ outp,
                          const float* __restrict__ bias, const float* __restrict__ mul) {
    const int lane = threadIdx.x & 63;
    const int w = threadIdx.x >> 6;
    const int i0 = blockIdx.y * 128 + w * 32;
    const int j0 = blockIdx.x * 64;
    const int lrow = lane & 15;
    const int lk = (lane >> 4) * 8;

    f32x4 acc[2][4];
#pragma unroll
    for (int a = 0; a < 2; ++a)
#pragma unroll
        for (int b = 0; b < 4; ++b) acc[a][b] = (f32x4){0.f, 0.f, 0.f, 0.f};

    for (int k0 = 0; k0 < K; k0 += 32) {
        bf16x8 af[2], bfr[4];
#pragma unroll
        for (int qs = 0; qs < 2; ++qs)
            af[qs] = *(const bf16x8*)(A + (size_t)(i0 + qs * 16 + lrow) * K + k0 + lk);
#pragma unroll
        for (int js = 0; js < 4; ++js)
            bfr[js] = *(const bf16x8*)(B + (size_t)(j0 + js * 16 + lrow) * K + k0 + lk);
#pragma unroll
        for (int qs = 0; qs < 2; ++qs)
#pragma unroll
            for (int js = 0; js < 4; ++js)
                acc[qs][js] = MFMA16(af[qs], bfr[js], acc[qs][js]);
    }

    const int rbase = (lane >> 4) * 4;
#pragma unroll
    for (int qs = 0; qs < 2; ++qs)
#pragma unroll
        for (int js = 0; js < 4; ++js)
#pragma unroll
            for (int r = 0; r < 4; ++r) {
                int i = i0 + qs * 16 + rbase + r;
                int j = j0 + js * 16 + lrow;
                float v = acc[qs][js][r];
                if (MODE == 0) {
                    ((bf16*)outp)[(size_t)(j >> 6) * (4096 * 64) + (size_t)i * 64 + (j & 63)] =
                        (bf16)(v * scale);
                } else if (MODE == 1) {
                    ((bf16*)outp)[(size_t)i * 4096 + j] = (bf16)v;
                } else if (MODE == 2) {
                    ((float*)outp)[(size_t)i * 4096 + j] = v + bias[i];
                } else {
                    float g = v + bias[i];
                    float sg = 1.f / (1.f + __expf(-g));
                    ((float*)outp)[(size_t)i * 4096 + j] = mul[(size_t)i * 4096 + j] * sg;
                }
            }
}

// ---------------------------------------------------------------------------
// K4: flash attention, KV-split S=4, static-max softmax (exp2, shift = 0).
// q: [8][4096][64] bf16 pre-scaled by (1/8)*log2(e); k: [8][4096][64];
// vT: [8][64][4096].  Swapped QK^T: S^T = mfma(K, Q) so each lane's 4 regs
// are 4 consecutive keys for one q-col -> vectorized b64 P-store to LDS.
// Row-sum l accumulated via MFMA with ones-operand (lands in C-layout).
// Partials: Opart bf16 [split][4096][512], lpart f32 [split][8][4096].
// grid = 1024 (split<<8 | h<<5 | qt), block = 256 (4 waves x 32 q-rows).
// ---------------------------------------------------------------------------
__launch_bounds__(256, 4)
__global__ void k_attn(const bf16* __restrict__ q, const bf16* __restrict__ k,
                       const bf16* __restrict__ vT, bf16* __restrict__ Opart,
                       float* __restrict__ lpart) {
    __shared__ bf16 plds[4][32 * 64];
    const int lane = threadIdx.x & 63;
    const int w = threadIdx.x >> 6;
    const int split = blockIdx.x >> 8;
    const int h = (blockIdx.x >> 5) & 7;
    const int qt = blockIdx.x & 31;
    const int qbase = qt * 128 + w * 32;
    const int lrow = lane & 15;
    const int g = lane >> 4;
    const int lk = g * 8;

    const bf16* qh = q + (size_t)h * 4096 * 64;
    const bf16* kh = k + (size_t)h * 4096 * 64;
    const bf16* vh = vT + (size_t)h * 64 * 4096;
    bf16* mylds = plds[w];

    // Q as B-fragments (col = q-row = lane&15)
    bf16x8 bq[2][2];
#pragma unroll
    for (int qs = 0; qs < 2; ++qs)
#pragma unroll
        for (int ks = 0; ks < 2; ++ks)
            bq[qs][ks] = *(const bf16x8*)(qh + (size_t)(qbase + qs * 16 + lrow) * 64 + ks * 32 + lk);

    f32x4 accO[2][4];
    f32x4 l_acc[2];
#pragma unroll
    for (int qs = 0; qs < 2; ++qs) {
#pragma unroll
        for (int ds = 0; ds < 4; ++ds) accO[qs][ds] = (f32x4){0.f, 0.f, 0.f, 0.f};
        l_acc[qs] = (f32x4){0.f, 0.f, 0.f, 0.f};
    }
    bf16x8 ones;
#pragma unroll
    for (int i = 0; i < 8; ++i) ones[i] = (bf16)1.0f;

    for (int t = 0; t < 16; ++t) {
        const int kb = split * 1024 + t * 64;

        // ---- S^T = K Q^T : s[qs][js][r] = S[key = js*16+4g+r][q = qs*16+lrow]
        f32x4 s[2][4];
#pragma unroll
        for (int qs = 0; qs < 2; ++qs)
#pragma unroll
            for (int js = 0; js < 4; ++js) s[qs][js] = (f32x4){0.f, 0.f, 0.f, 0.f};
#pragma unroll
        for (int ks = 0; ks < 2; ++ks) {
            bf16x8 ak[4];
#pragma unroll
            for (int js = 0; js < 4; ++js)
                ak[js] = *(const bf16x8*)(kh + (size_t)(kb + js * 16 + lrow) * 64 + ks * 32 + lk);
#pragma unroll
            for (int qs = 0; qs < 2; ++qs)
#pragma unroll
                for (int js = 0; js < 4; ++js)
                    s[qs][js] = MFMA16(ak[js], bq[qs][ks], s[qs][js]);
        }

        // ---- P = exp2(s) -> LDS (b64 stores, XOR-swizzled rows) ----
#pragma unroll
        for (int qs = 0; qs < 2; ++qs) {
            const int qrow = qs * 16 + lrow;
            const int swz = (qrow & 7) << 4;
#pragma unroll
            for (int js = 0; js < 4; ++js) {
                bf16x4 pk;
#pragma unroll
                for (int r = 0; r < 4; ++r) pk[r] = (bf16)fexp2(s[qs][js][r]);
                *(bf16x4*)((char*)mylds + ((qrow * 128 + js * 32 + g * 8) ^ swz)) = pk;
            }
        }

        // ---- O += P V ; l += P @ ones ----
#pragma unroll
        for (int ks2 = 0; ks2 < 2; ++ks2) {
            bf16x8 ap[2], bv[4];
#pragma unroll
            for (int qs = 0; qs < 2; ++qs) {
                const int row = qs * 16 + lrow;
                ap[qs] = *(const bf16x8*)((char*)mylds +
                                          ((row * 128 + ks2 * 64 + g * 16) ^ ((row & 7) << 4)));
            }
#pragma unroll
            for (int ds = 0; ds < 4; ++ds)
                bv[ds] = *(const bf16x8*)(vh + (size_t)(ds * 16 + lrow) * 4096 + kb + ks2 * 32 + lk);
#pragma unroll
            for (int qs = 0; qs < 2; ++qs) {
#pragma unroll
                for (int ds = 0; ds < 4; ++ds)
                    accO[qs][ds] = MFMA16(ap[qs], bv[ds], accO[qs][ds]);
                l_acc[qs] = MFMA16(ap[qs], ones, l_acc[qs]);
            }
        }
    }

    // ---- store partials (unnormalized) ----
#pragma unroll
    for (int qs = 0; qs < 2; ++qs)
#pragma unroll
        for (int ds = 0; ds < 4; ++ds)
#pragma unroll
            for (int r = 0; r < 4; ++r) {
                const int n = qbase + qs * 16 + 4 * g + r;
                Opart[((size_t)split * 4096 + n) * 512 + h * 64 + ds * 16 + lrow] =
                    (bf16)accO[qs][ds][r];
            }
    if (lrow == 0) {
#pragma unroll
        for (int qs = 0; qs < 2; ++qs)
#pragma unroll
            for (int r = 0; r < 4; ++r)
                lpart[((size_t)split * 8 + h) * 4096 + qbase + qs * 16 + 4 * g + r] =
                    l_acc[qs][r];
    }
}

// ---------------------------------------------------------------------------
// K5: combine partials -> o_buf bf16 [4096][512]
// ---------------------------------------------------------------------------
__global__ void k_combine(const bf16* __restrict__ Opart, const float* __restrict__ lpart,
                          bf16* __restrict__ o) {
    const int tid = blockIdx.x * 256 + threadIdx.x;   // 262144
    const int n = tid >> 6;
    const int c8 = (tid & 63) * 8;
    const int h = c8 >> 6;
    float acc[8] = {0, 0, 0, 0, 0, 0, 0, 0};
    float l = 0.f;
#pragma unroll
    for (int s = 0; s < 4; ++s) {
        const bf16x8 v = *(const bf16x8*)(Opart + ((size_t)s * 4096 + n) * 512 + c8);
#pragma unroll
        for (int j = 0; j < 8; ++j) acc[j] += (float)v[j];
        l += lpart[((size_t)s * 8 + h) * 4096 + n];
    }
    const float inv = 1.f / l;
    bf16x8 ov;
#pragma unroll
    for (int j = 0; j < 8; ++j) ov[j] = (bf16)(acc[j] * inv);
    *(bf16x8*)(o + (size_t)n * 512 + c8) = ov;
}

// ---------------------------------------------------------------------------
// K6: depthwise 3x3 conv (SAME).
// ---------------------------------------------------------------------------
__global__ void k_dw(const float* __restrict__ y, const float* __restrict__ wdw,
                     const float* __restrict__ bdw, float* __restrict__ dwout,
                     bf16* __restrict__ dwt) {
    int t = blockIdx.x * 256 + threadIdx.x;   // 1M
    int c = t >> 12, n = t & 4095, yy = n >> 6, xx = n & 63;
    float acc = bdw[c];
    const float* yc = y + (size_t)c * 4096;
#pragma unroll
    for (int ky = 0; ky < 3; ++ky) {
        int ry = yy + ky - 1;
        if ((unsigned)ry < 64u) {
#pragma unroll
            for (int kx = 0; kx < 3; ++kx) {
                int rx = xx + kx - 1;
                if ((unsigned)rx < 64u) acc += wdw[c * 9 + ky * 3 + kx] * yc[ry * 64 + rx];
            }
        }
    }
    dwout[t] = acc;
    dwt[n * 256 + c] = (bf16)acc;
}

// ---------------------------------------------------------------------------
extern "C" void kernel_launch(void* const* d_in, const int* in_sizes, int n_in,
                              void* d_out, int out_size, void* d_ws, size_t ws_size,
                              hipStream_t stream) {
    const float* x   = (const float*)d_in[0];
    const float* wq1 = (const float*)d_in[1];
    const float* wk1 = (const float*)d_in[2];
    const float* wv1 = (const float*)d_in[3];
    const float* wq2 = (const float*)d_in[4];
    const float* wk2 = (const float*)d_in[5];
    const float* wv2 = (const float*)d_in[6];
    const float* wo  = (const float*)d_in[7];
    const float* bo  = (const float*)d_in[8];
    const float* wdw = (const float*)d_in[9];
    const float* bdw = (const float*)d_in[10];
    const float* wg  = (const float*)d_in[11];
    const float* bg  = (const float*)d_in[12];

    char* ws = (char*)d_ws;
    size_t off = 0;
    auto alloc = [&](size_t bytes) {
        char* p = ws + off;
        off += (bytes + 255) & ~(size_t)255;
        return p;
    };
    // persistent
    bf16*  q_buf = (bf16*)alloc((size_t)8 * 4096 * 64 * 2);   // 4MB
    bf16*  k_buf = (bf16*)alloc((size_t)8 * 4096 * 64 * 2);   // 4MB
    bf16*  vT    = (bf16*)alloc((size_t)8 * 64 * 4096 * 2);   // 4MB
    bf16*  o_buf = (bf16*)alloc((size_t)4096 * 512 * 2);      // 4MB
    bf16*  wo_bf = (bf16*)alloc((size_t)256 * 512 * 2);
    bf16*  wg_bf = (bf16*)alloc((size_t)256 * 256 * 2);
    // union region (lifetimes disjoint):
    char* U = ws + off;
    //   phase 1 (pre-attention): xbf, Wq, Wk, Wv
    bf16*  xbf = (bf16*)U;                                     // 2MB
    bf16*  Wq  = (bf16*)(U + (size_t)2 * 1024 * 1024);
    bf16*  Wk  = (bf16*)(U + (size_t)2 * 1024 * 1024 + 262144);
    bf16*  Wv  = (bf16*)(U + (size_t)2 * 1024 * 1024 + 524288);
    //   phase 2 (attention): Opart, lpart
    bf16*  Opart = (bf16*)U;                                   // 16MB
    float* lpart = (float*)(U + (size_t)16 * 1024 * 1024);     // 512KB
    //   phase 3 (post-attention): ybuf, dwout, dwt
    float* ybuf  = (float*)U;                                  // 4MB
    float* dwout = (float*)(U + (size_t)4 * 1024 * 1024);      // 4MB
    bf16*  dwt   = (bf16*)(U + (size_t)8 * 1024 * 1024);       // 2MB
    (void)ws_size; (void)in_sizes; (void)n_in; (void)out_size;

    const float QSCALE = 0.125f * 1.4426950408889634f;  // fold 1/sqrt(dk) * log2(e)

    k_transpose_x<<<256, 256, 0, stream>>>(x, xbf);
    k_prep_w<<<2304, 256, 0, stream>>>(wq1, wk1, wv1, wq2, wk2, wv2, wo, wg,
                                       Wq, Wk, Wv, wo_bf, wg_bf);
    k_gemm_nt<0><<<dim3(8, 32), 256, 0, stream>>>(xbf, Wq, 256, QSCALE, q_buf, nullptr, nullptr);
    k_gemm_nt<0><<<dim3(8, 32), 256, 0, stream>>>(xbf, Wk, 256, 1.0f, k_buf, nullptr, nullptr);
    k_gemm_nt<1><<<dim3(64, 4), 256, 0, stream>>>(Wv, xbf, 256, 1.0f, vT, nullptr, nullptr);
    k_attn<<<1024, 256, 0, stream>>>(q_buf, k_buf, vT, Opart, lpart);
    k_combine<<<1024, 256, 0, stream>>>(Opart, lpart, o_buf);
    k_gemm_nt<2><<<dim3(64, 2), 256, 0, stream>>>(wo_bf, o_buf, 512, 1.0f, ybuf, bo, nullptr);
    k_dw<<<4096, 256, 0, stream>>>(ybuf, wdw, bdw, dwout, dwt);
    k_gemm_nt<3><<<dim3(64, 2), 256, 0, stream>>>(wg_bf, dwt, 256, 1.0f, d_out, bg, dwout);
}

// Round 5
// 190.562 us; speedup vs baseline: 1.3193x; 1.0365x over previous
//
#include <hip/hip_runtime.h>

typedef __bf16 bf16;
typedef __bf16 bf16x4 __attribute__((ext_vector_type(4)));
typedef __bf16 bf16x8 __attribute__((ext_vector_type(8)));
typedef float f32x4 __attribute__((ext_vector_type(4)));

#define MFMA16(a, b, c) __builtin_amdgcn_mfma_f32_16x16x32_bf16((a), (b), (c), 0, 0, 0)

__device__ inline float fexp2(float x) {
    float r;
    asm("v_exp_f32 %0, %1" : "=v"(r) : "v"(x));
    return r;
}

// ---------------------------------------------------------------------------
// K1: transpose x [256][4096] f32 -> xt [4096][256] bf16, LDS-tiled 64x64.
// ---------------------------------------------------------------------------
__global__ void k_transpose_x(const float* __restrict__ x, bf16* __restrict__ xt) {
    __shared__ float tile[64][68];
    const int t = threadIdx.x;
    const int c0 = (blockIdx.x & 3) * 64;
    const int n0 = (blockIdx.x >> 2) * 64;
    {
        const int cr = t >> 4, nc = (t & 15) * 4;
#pragma unroll
        for (int i = 0; i < 4; ++i) {
            const float4 v = *(const float4*)(x + (size_t)(c0 + cr + i * 16) * 4096 + n0 + nc);
            tile[cr + i * 16][nc + 0] = v.x;
            tile[cr + i * 16][nc + 1] = v.y;
            tile[cr + i * 16][nc + 2] = v.z;
            tile[cr + i * 16][nc + 3] = v.w;
        }
    }
    __syncthreads();
    const int n = t >> 2, cc = (t & 3) * 16;
    bf16x8 o0, o1;
#pragma unroll
    for (int j = 0; j < 8; ++j) o0[j] = (bf16)tile[cc + j][n];
#pragma unroll
    for (int j = 0; j < 8; ++j) o1[j] = (bf16)tile[cc + 8 + j][n];
    bf16* dst = xt + (size_t)(n0 + n) * 256 + c0 + cc;
    *(bf16x8*)dst = o0;
    *(bf16x8*)(dst + 8) = o1;
}

// ---------------------------------------------------------------------------
// K2: fused weights Wq/Wk/Wv = w2 @ w1  [512][256] bf16, plus wo/wg -> bf16
// ---------------------------------------------------------------------------
__global__ void k_prep_w(const float* __restrict__ wq1, const float* __restrict__ wk1,
                         const float* __restrict__ wv1, const float* __restrict__ wq2,
                         const float* __restrict__ wk2, const float* __restrict__ wv2,
                         const float* __restrict__ wo, const float* __restrict__ wg,
                         bf16* __restrict__ Wq, bf16* __restrict__ Wk, bf16* __restrict__ Wv,
                         bf16* __restrict__ wo_bf, bf16* __restrict__ wg_bf) {
    int t = blockIdx.x * 256 + threadIdx.x;
    if (t < 393216) {                       // 3 * 512 * 256
        int which = t >> 17;
        int rem = t & 131071;
        int o = rem >> 8, c = rem & 255;
        const float* w1 = which == 0 ? wq1 : which == 1 ? wk1 : wv1;
        const float* w2 = which == 0 ? wq2 : which == 1 ? wk2 : wv2;
        float acc = 0.f;
#pragma unroll
        for (int j = 0; j < 32; ++j) acc += w2[o * 32 + j] * w1[j * 256 + c];
        bf16* W = which == 0 ? Wq : which == 1 ? Wk : Wv;
        W[o * 256 + c] = (bf16)acc;
    } else if (t < 524288) {                // wo: 256*512
        int idx = t - 393216;
        wo_bf[idx] = (bf16)wo[idx];
    } else if (t < 589824) {                // wg: 256*256
        int idx = t - 524288;
        wg_bf[idx] = (bf16)wg[idx];
    }
}

// ---------------------------------------------------------------------------
// Generic GEMM-NT: C[i][j] = sum_k A[i][k] * B[j][k].  A:[M][K] B:[N][K] bf16.
// ---------------------------------------------------------------------------
template <int MODE>
__launch_bounds__(256)
__global__ void k_gemm_nt(const bf16* __restrict__ A, const bf16* __restrict__ B,
                          int K, float scale, void* __restrict__ outp,
                          const float* __restrict__ bias, const float* __restrict__ mul) {
    const int lane = threadIdx.x & 63;
    const int w = threadIdx.x >> 6;
    const int i0 = blockIdx.y * 128 + w * 32;
    const int j0 = blockIdx.x * 64;
    const int lrow = lane & 15;
    const int lk = (lane >> 4) * 8;

    f32x4 acc[2][4];
#pragma unroll
    for (int a = 0; a < 2; ++a)
#pragma unroll
        for (int b = 0; b < 4; ++b) acc[a][b] = (f32x4){0.f, 0.f, 0.f, 0.f};

    for (int k0 = 0; k0 < K; k0 += 32) {
        bf16x8 af[2], bfr[4];
#pragma unroll
        for (int qs = 0; qs < 2; ++qs)
            af[qs] = *(const bf16x8*)(A + (size_t)(i0 + qs * 16 + lrow) * K + k0 + lk);
#pragma unroll
        for (int js = 0; js < 4; ++js)
            bfr[js] = *(const bf16x8*)(B + (size_t)(j0 + js * 16 + lrow) * K + k0 + lk);
#pragma unroll
        for (int qs = 0; qs < 2; ++qs)
#pragma unroll
            for (int js = 0; js < 4; ++js)
                acc[qs][js] = MFMA16(af[qs], bfr[js], acc[qs][js]);
    }

    const int rbase = (lane >> 4) * 4;
#pragma unroll
    for (int qs = 0; qs < 2; ++qs)
#pragma unroll
        for (int js = 0; js < 4; ++js)
#pragma unroll
            for (int r = 0; r < 4; ++r) {
                int i = i0 + qs * 16 + rbase + r;
                int j = j0 + js * 16 + lrow;
                float v = acc[qs][js][r];
                if (MODE == 0) {
                    ((bf16*)outp)[(size_t)(j >> 6) * (4096 * 64) + (size_t)i * 64 + (j & 63)] =
                        (bf16)(v * scale);
                } else if (MODE == 1) {
                    ((bf16*)outp)[(size_t)i * 4096 + j] = (bf16)v;
                } else if (MODE == 2) {
                    ((float*)outp)[(size_t)i * 4096 + j] = v + bias[i];
                } else {
                    float g = v + bias[i];
                    float sg = 1.f / (1.f + __expf(-g));
                    ((float*)outp)[(size_t)i * 4096 + j] = mul[(size_t)i * 4096 + j] * sg;
                }
            }
}

// ---------------------------------------------------------------------------
// K4: flash attention, KV-split S=4, static-max softmax (exp2, shift=0).
// Cooperative double-buffered LDS staging of K/V tiles (XOR-swizzled rows),
// software-pipelined global->reg->LDS (issue-early / write-late, T14).
// q pre-scaled by (1/8)*log2(e).  LDS: KV 16KB + P 4x4KB = 32KB.
// grid = 1024 (split<<8 | h<<5 | qt), block = 256 (4 waves x 32 q-rows).
// ---------------------------------------------------------------------------
__launch_bounds__(256, 4)
__global__ void k_attn(const bf16* __restrict__ q, const bf16* __restrict__ k,
                       const bf16* __restrict__ vT, bf16* __restrict__ Opart,
                       float* __restrict__ lpart) {
    __shared__ char kvlds[16384];           // K [64 rows][128B] at 0, V at 8192
    __shared__ char plds[4][4096];          // per-wave P [32 rows][128B]
    const int tid = threadIdx.x;
    const int lane = tid & 63;
    const int w = tid >> 6;
    const int split = blockIdx.x >> 8;
    const int h = (blockIdx.x >> 5) & 7;
    const int qt = blockIdx.x & 31;
    const int qbase = qt * 128 + w * 32;
    const int lrow = lane & 15;
    const int g = lane >> 4;
    const int swzr = (lrow & 7) << 4;

    const bf16* qh = q + (size_t)h * 4096 * 64;
    const bf16* kh = k + (size_t)h * 4096 * 64;
    const bf16* vh = vT + (size_t)h * 64 * 4096;
    char* myp = plds[w];
    const char* Kl = kvlds;
    const char* Vl = kvlds + 8192;

    // staging geometry: threads 0-127 stage K (8KB), 128-255 stage V (8KB);
    // each thread owns one 64B half-row (4 x 16B units).
    const int isV = tid >> 7;
    const int srow = (tid & 127) >> 1;
    const int shalf = tid & 1;
    const int swzs = (srow & 7) << 4;
    char* ldst = kvlds + isV * 8192 + srow * 128;

    auto load_tile = [&](int t, uint4 r[4]) {
        const int kb = split * 1024 + t * 64;
        const bf16* p = isV ? (vh + (size_t)srow * 4096 + kb + shalf * 32)
                            : (kh + (size_t)(kb + srow) * 64 + shalf * 32);
#pragma unroll
        for (int u = 0; u < 4; ++u) r[u] = *(const uint4*)(p + u * 8);
    };
    auto write_tile = [&](uint4 r[4]) {
#pragma unroll
        for (int u = 0; u < 4; ++u)
            *(uint4*)(ldst + ((shalf * 64 + u * 16) ^ swzs)) = r[u];
    };

    // Q as B-fragments (col = q-row = lane&15)
    bf16x8 bq[2][2];
#pragma unroll
    for (int qs = 0; qs < 2; ++qs)
#pragma unroll
        for (int ks = 0; ks < 2; ++ks)
            bq[qs][ks] = *(const bf16x8*)(qh + (size_t)(qbase + qs * 16 + lrow) * 64 +
                                          ks * 32 + g * 8);

    f32x4 accO[2][4];
    float lsum[2] = {0.f, 0.f};
#pragma unroll
    for (int qs = 0; qs < 2; ++qs)
#pragma unroll
        for (int ds = 0; ds < 4; ++ds) accO[qs][ds] = (f32x4){0.f, 0.f, 0.f, 0.f};

    auto compute = [&]() {
        // ---- S^T = K Q^T ----
        f32x4 s[2][4];
#pragma unroll
        for (int qs = 0; qs < 2; ++qs)
#pragma unroll
            for (int js = 0; js < 4; ++js) s[qs][js] = (f32x4){0.f, 0.f, 0.f, 0.f};
#pragma unroll
        for (int ks = 0; ks < 2; ++ks) {
            bf16x8 ak[4];
#pragma unroll
            for (int js = 0; js < 4; ++js)
                ak[js] = *(const bf16x8*)(Kl + (js * 16 + lrow) * 128 +
                                          ((ks * 64 + g * 16) ^ swzr));
#pragma unroll
            for (int qs = 0; qs < 2; ++qs)
#pragma unroll
                for (int js = 0; js < 4; ++js)
                    s[qs][js] = MFMA16(ak[js], bq[qs][ks], s[qs][js]);
        }
        // ---- P = exp2(s) -> per-wave LDS; lsum += P ----
#pragma unroll
        for (int qs = 0; qs < 2; ++qs) {
            const int qrow = qs * 16 + lrow;
#pragma unroll
            for (int js = 0; js < 4; ++js) {
                bf16x4 pk;
#pragma unroll
                for (int r = 0; r < 4; ++r) {
                    float e = fexp2(s[qs][js][r]);
                    lsum[qs] += e;
                    pk[r] = (bf16)e;
                }
                *(bf16x4*)(myp + ((qrow * 128 + js * 32 + g * 8) ^ swzr)) = pk;
            }
        }
        // ---- O += P V ----
#pragma unroll
        for (int ks2 = 0; ks2 < 2; ++ks2) {
            bf16x8 ap[2], bv[4];
#pragma unroll
            for (int qs = 0; qs < 2; ++qs)
                ap[qs] = *(const bf16x8*)(myp + (((qs * 16 + lrow) * 128 + ks2 * 64 + g * 16) ^
                                                swzr));
#pragma unroll
            for (int ds = 0; ds < 4; ++ds)
                bv[ds] = *(const bf16x8*)(Vl + (ds * 16 + lrow) * 128 +
                                          ((ks2 * 64 + g * 16) ^ swzr));
#pragma unroll
            for (int qs = 0; qs < 2; ++qs)
#pragma unroll
                for (int ds = 0; ds < 4; ++ds)
                    accO[qs][ds] = MFMA16(ap[qs], bv[ds], accO[qs][ds]);
        }
    };

    // ---- pipelined main loop: 16 tiles, 2 per iteration ----
    uint4 rA[4], rB[4];
    load_tile(0, rA);
    for (int tt = 0; tt < 8; ++tt) {
        write_tile(rA);
        load_tile(2 * tt + 1, rB);
        __syncthreads();
        compute();
        __syncthreads();
        write_tile(rB);
        if (tt < 7) load_tile(2 * tt + 2, rA);
        __syncthreads();
        compute();
        __syncthreads();
    }

    // ---- store partials (unnormalized) ----
#pragma unroll
    for (int qs = 0; qs < 2; ++qs)
#pragma unroll
        for (int ds = 0; ds < 4; ++ds)
#pragma unroll
            for (int r = 0; r < 4; ++r) {
                const int n = qbase + qs * 16 + 4 * g + r;
                Opart[((size_t)split * 4096 + n) * 512 + h * 64 + ds * 16 + lrow] =
                    (bf16)accO[qs][ds][r];
            }
#pragma unroll
    for (int qs = 0; qs < 2; ++qs) {
        float lv = lsum[qs];
        lv += __shfl_xor(lv, 16);
        lv += __shfl_xor(lv, 32);
        if (lane < 16)
            lpart[((size_t)split * 8 + h) * 4096 + qbase + qs * 16 + lane] = lv;
    }
}

// ---------------------------------------------------------------------------
// K5: combine partials -> o_buf bf16 [4096][512]
// ---------------------------------------------------------------------------
__global__ void k_combine(const bf16* __restrict__ Opart, const float* __restrict__ lpart,
                          bf16* __restrict__ o) {
    const int tid = blockIdx.x * 256 + threadIdx.x;   // 262144
    const int n = tid >> 6;
    const int c8 = (tid & 63) * 8;
    const int h = c8 >> 6;
    float acc[8] = {0, 0, 0, 0, 0, 0, 0, 0};
    float l = 0.f;
#pragma unroll
    for (int s = 0; s < 4; ++s) {
        const bf16x8 v = *(const bf16x8*)(Opart + ((size_t)s * 4096 + n) * 512 + c8);
#pragma unroll
        for (int j = 0; j < 8; ++j) acc[j] += (float)v[j];
        l += lpart[((size_t)s * 8 + h) * 4096 + n];
    }
    const float inv = 1.f / l;
    bf16x8 ov;
#pragma unroll
    for (int j = 0; j < 8; ++j) ov[j] = (bf16)(acc[j] * inv);
    *(bf16x8*)(o + (size_t)n * 512 + c8) = ov;
}

// ---------------------------------------------------------------------------
// K6: depthwise 3x3 conv (SAME).
// ---------------------------------------------------------------------------
__global__ void k_dw(const float* __restrict__ y, const float* __restrict__ wdw,
                     const float* __restrict__ bdw, float* __restrict__ dwout,
                     bf16* __restrict__ dwt) {
    int t = blockIdx.x * 256 + threadIdx.x;   // 1M
    int c = t >> 12, n = t & 4095, yy = n >> 6, xx = n & 63;
    float acc = bdw[c];
    const float* yc = y + (size_t)c * 4096;
#pragma unroll
    for (int ky = 0; ky < 3; ++ky) {
        int ry = yy + ky - 1;
        if ((unsigned)ry < 64u) {
#pragma unroll
            for (int kx = 0; kx < 3; ++kx) {
                int rx = xx + kx - 1;
                if ((unsigned)rx < 64u) acc += wdw[c * 9 + ky * 3 + kx] * yc[ry * 64 + rx];
            }
        }
    }
    dwout[t] = acc;
    dwt[n * 256 + c] = (bf16)acc;
}

// ---------------------------------------------------------------------------
extern "C" void kernel_launch(void* const* d_in, const int* in_sizes, int n_in,
                              void* d_out, int out_size, void* d_ws, size_t ws_size,
                              hipStream_t stream) {
    const float* x   = (const float*)d_in[0];
    const float* wq1 = (const float*)d_in[1];
    const float* wk1 = (const float*)d_in[2];
    const float* wv1 = (const float*)d_in[3];
    const float* wq2 = (const float*)d_in[4];
    const float* wk2 = (const float*)d_in[5];
    const float* wv2 = (const float*)d_in[6];
    const float* wo  = (const float*)d_in[7];
    const float* bo  = (const float*)d_in[8];
    const float* wdw = (const float*)d_in[9];
    const float* bdw = (const float*)d_in[10];
    const float* wg  = (const float*)d_in[11];
    const float* bg  = (const float*)d_in[12];

    char* ws = (char*)d_ws;
    size_t off = 0;
    auto alloc = [&](size_t bytes) {
        char* p = ws + off;
        off += (bytes + 255) & ~(size_t)255;
        return p;
    };
    // persistent
    bf16*  q_buf = (bf16*)alloc((size_t)8 * 4096 * 64 * 2);
    bf16*  k_buf = (bf16*)alloc((size_t)8 * 4096 * 64 * 2);
    bf16*  vT    = (bf16*)alloc((size_t)8 * 64 * 4096 * 2);
    bf16*  o_buf = (bf16*)alloc((size_t)4096 * 512 * 2);
    bf16*  wo_bf = (bf16*)alloc((size_t)256 * 512 * 2);
    bf16*  wg_bf = (bf16*)alloc((size_t)256 * 256 * 2);
    // union region (lifetimes disjoint):
    char* U = ws + off;
    bf16*  xbf = (bf16*)U;
    bf16*  Wq  = (bf16*)(U + (size_t)2 * 1024 * 1024);
    bf16*  Wk  = (bf16*)(U + (size_t)2 * 1024 * 1024 + 262144);
    bf16*  Wv  = (bf16*)(U + (size_t)2 * 1024 * 1024 + 524288);
    bf16*  Opart = (bf16*)U;                                   // 16MB
    float* lpart = (float*)(U + (size_t)16 * 1024 * 1024);     // 512KB
    float* ybuf  = (float*)U;
    float* dwout = (float*)(U + (size_t)4 * 1024 * 1024);
    bf16*  dwt   = (bf16*)(U + (size_t)8 * 1024 * 1024);
    (void)ws_size; (void)in_sizes; (void)n_in; (void)out_size;

    const float QSCALE = 0.125f * 1.4426950408889634f;  // fold 1/sqrt(dk) * log2(e)

    k_transpose_x<<<256, 256, 0, stream>>>(x, xbf);
    k_prep_w<<<2304, 256, 0, stream>>>(wq1, wk1, wv1, wq2, wk2, wv2, wo, wg,
                                       Wq, Wk, Wv, wo_bf, wg_bf);
    k_gemm_nt<0><<<dim3(8, 32), 256, 0, stream>>>(xbf, Wq, 256, QSCALE, q_buf, nullptr, nullptr);
    k_gemm_nt<0><<<dim3(8, 32), 256, 0, stream>>>(xbf, Wk, 256, 1.0f, k_buf, nullptr, nullptr);
    k_gemm_nt<1><<<dim3(64, 4), 256, 0, stream>>>(Wv, xbf, 256, 1.0f, vT, nullptr, nullptr);
    k_attn<<<1024, 256, 0, stream>>>(q_buf, k_buf, vT, Opart, lpart);
    k_combine<<<1024, 256, 0, stream>>>(Opart, lpart, o_buf);
    k_gemm_nt<2><<<dim3(64, 2), 256, 0, stream>>>(wo_bf, o_buf, 512, 1.0f, ybuf, bo, nullptr);
    k_dw<<<4096, 256, 0, stream>>>(ybuf, wdw, bdw, dwout, dwt);
    k_gemm_nt<3><<<dim3(64, 2), 256, 0, stream>>>(wg_bf, dwt, 256, 1.0f, d_out, bg, dwout);
}